// Round 17
// baseline (183.861 us; speedup 1.0000x reference)
//
#include <hip/hip_runtime.h>
#include <hip/hip_fp16.h>

// ---------------------------------------------------------------------------
// GCN layer: out[b][f][t][n] = relu( rsqrt(deg_in[n]) *
//     sum_{e: dst[e]=n} ( rsqrt(deg_out[src[e]]) * x[src[e]] @ W )[b][t][f] + bias[f] )
// Strategy: (1) degrees+CSR, (2) MFMA transform -> y[n][512] fp16 plain
//           node-major, (3) CSR gather-sum + epilogue + transpose-back.
// R17: single change — aggregate's out-writes become NONTEMPORAL stores.
//      Hypothesis: the 100MB out stream allocates in L2/L3 and evicts y
//      (51MB), causing the 191MB FETCH (vs ~51MB ideal) seen every round.
//      NT stores keep y L3-resident. Go/no-go: FETCH <= 90MB.
//      Transform = R16 (MFMA, 2-wave blocks, cross-bt prefetch).
//      Aggregate body = R9 (2x8B/edge, unroll 4 — measured best).
// ---------------------------------------------------------------------------

typedef _Float16 half8 __attribute__((ext_vector_type(8)));
typedef float f32x4 __attribute__((ext_vector_type(4)));

extern "C" __global__ void k_deg(const int* __restrict__ src, const int* __restrict__ dst,
                                 int* __restrict__ deg_out, int* __restrict__ deg_in, int E) {
  int e = blockIdx.x * blockDim.x + threadIdx.x;
  if (e < E) {
    atomicAdd(&deg_out[src[e]], 1);
    atomicAdd(&deg_in[dst[e]], 1);
  }
}

// scan1 + rsqrt fused: block sums of deg_in, plus rs arrays.
extern "C" __global__ __launch_bounds__(256) void k_scan1(const int* __restrict__ deg_in,
                                                          const int* __restrict__ deg_out,
                                                          int* __restrict__ bsum,
                                                          float* __restrict__ rs_out,
                                                          float* __restrict__ rs_in, int N) {
  __shared__ int red[256];
  int tid = threadIdx.x;
  int i = blockIdx.x * 256 + tid;
  int di = (i < N) ? deg_in[i] : 0;
  red[tid] = di;
  if (i < N) {
    int a = deg_out[i] > 1 ? deg_out[i] : 1;
    int b = di > 1 ? di : 1;
    rs_out[i] = rsqrtf((float)a);
    rs_in[i]  = rsqrtf((float)b);
  }
  __syncthreads();
  #pragma unroll
  for (int off = 128; off > 0; off >>= 1) {
    if (tid < off) red[tid] += red[tid + off];
    __syncthreads();
  }
  if (tid == 0) bsum[blockIdx.x] = red[0];
}

extern "C" __global__ __launch_bounds__(256) void k_scan2(const int* __restrict__ bsum,
                                                          int* __restrict__ boffs,
                                                          int* __restrict__ offs, int M, int N) {
  __shared__ int sc[256];
  int tid = threadIdx.x;
  int v = (tid < M) ? bsum[tid] : 0;
  sc[tid] = v;
  __syncthreads();
  #pragma unroll
  for (int off = 1; off < 256; off <<= 1) {
    int t = sc[tid];
    if (tid >= off) t += sc[tid - off];
    __syncthreads();
    sc[tid] = t;
    __syncthreads();
  }
  boffs[tid] = sc[tid] - v;           // exclusive block offset
  if (tid == 255) offs[N] = sc[255];  // total edge count
}

extern "C" __global__ __launch_bounds__(256) void k_scan3(const int* __restrict__ deg,
                                                          const int* __restrict__ boffs,
                                                          int* __restrict__ offs, int N) {
  __shared__ int sc[256];
  int tid = threadIdx.x;
  int i = blockIdx.x * 256 + tid;
  int v = (i < N) ? deg[i] : 0;
  sc[tid] = v;
  __syncthreads();
  #pragma unroll
  for (int off = 1; off < 256; off <<= 1) {
    int t = sc[tid];
    if (tid >= off) t += sc[tid - off];
    __syncthreads();
    sc[tid] = t;
    __syncthreads();
  }
  if (i < N) offs[i] = boffs[blockIdx.x] + sc[tid] - v;
}

extern "C" __global__ void k_scatter(const int* __restrict__ src, const int* __restrict__ dst,
                                     const int* __restrict__ offs, int* __restrict__ cursor,
                                     int* __restrict__ csr_src, int E) {
  int e = blockIdx.x * blockDim.x + threadIdx.x;
  if (e < E) {
    int d = dst[e];
    int pos = offs[d] + atomicAdd(&cursor[d], 1);
    csr_src[pos] = src[e];
  }
}

// MFMA transform (R16). Block = 128 thr = 2 waves; grid (N/16, 2). Wave w of
// block (blockIdx.y, w) handles bt = blockIdx.y*4 + w*2 + {0,1} for 16 nodes.
// W frags preloaded in VGPRs; A-frags for bt+1 prefetched during bt's MFMAs.
extern "C" __global__ __launch_bounds__(128) void k_transform(
    const float* __restrict__ in_feat, const float* __restrict__ W,
    const float* __restrict__ rs_out, __half* __restrict__ y, int N) {
  int tid = threadIdx.x;
  int wave = tid >> 6, l = tid & 63;
  int col = l & 15;      // A row (node) on load side; D col (f) on store side
  int kg  = l >> 4;      // k-group 0..3
  int n0 = blockIdx.x * 16;
  int btbase = blockIdx.y * 4 + wave * 2;   // bt = btbase, btbase+1

  half8 wf[4][2];
  #pragma unroll
  for (int ft = 0; ft < 4; ++ft)
    #pragma unroll
    for (int ks = 0; ks < 2; ++ks)
      #pragma unroll
      for (int j = 0; j < 8; ++j)
        wf[ft][ks][j] = (_Float16)W[(ks * 32 + kg * 8 + j) * 64 + ft * 16 + col];

  int nA = n0 + col;
  bool okA = (nA < N);
  float rs = okA ? rs_out[nA] : 0.0f;
  size_t hs = (size_t)4 * (size_t)N;

  float c0[8], c1[8], nx0[8], nx1[8];
  {
    int bt = btbase, b = bt >> 2, t = bt & 3;
    const float* xp = in_feat + (size_t)(b * 256 + t) * (size_t)N + nA;
    #pragma unroll
    for (int j = 0; j < 8; ++j) c0[j] = okA ? xp[(size_t)(kg * 8 + j) * hs] : 0.0f;
    #pragma unroll
    for (int j = 0; j < 8; ++j) c1[j] = okA ? xp[(size_t)(32 + kg * 8 + j) * hs] : 0.0f;
  }

  #pragma unroll
  for (int p = 0; p < 2; ++p) {
    if (p == 0) {  // prefetch bt+1's A-fragments before consuming bt's
      int bt = btbase + 1, b = bt >> 2, t = bt & 3;
      const float* xp = in_feat + (size_t)(b * 256 + t) * (size_t)N + nA;
      #pragma unroll
      for (int j = 0; j < 8; ++j) nx0[j] = okA ? xp[(size_t)(kg * 8 + j) * hs] : 0.0f;
      #pragma unroll
      for (int j = 0; j < 8; ++j) nx1[j] = okA ? xp[(size_t)(32 + kg * 8 + j) * hs] : 0.0f;
    }
    int bt = btbase + p;

    half8 a0, a1;
    #pragma unroll
    for (int j = 0; j < 8; ++j) {
      a0[j] = (_Float16)(c0[j] * rs);
      a1[j] = (_Float16)(c1[j] * rs);
    }

    #pragma unroll
    for (int ft = 0; ft < 4; ++ft) {
      f32x4 acc = {0.f, 0.f, 0.f, 0.f};
      acc = __builtin_amdgcn_mfma_f32_16x16x32_f16(a0, wf[ft][0], acc, 0, 0, 0);
      acc = __builtin_amdgcn_mfma_f32_16x16x32_f16(a1, wf[ft][1], acc, 0, 0, 0);
      #pragma unroll
      for (int r = 0; r < 4; ++r) {
        int nr = n0 + kg * 4 + r;
        if (nr < N)
          y[(size_t)nr * 512 + bt * 64 + ft * 16 + col] = __float2half(acc[r]);
      }
    }

    if (p == 0) {
      #pragma unroll
      for (int j = 0; j < 8; ++j) { c0[j] = nx0[j]; c1[j] = nx1[j]; }
    }
  }
}

// Aggregate (R9 body; R17: NONTEMPORAL out stores). 512 threads = 8 waves;
// wave handles 2 nodes (16-node tile, 33KB LDS -> 4 blocks/CU). Per edge:
// 2x8B loads (channels 4l..4l+3 and 256+4l..+3), unroll 4.
extern "C" __global__ __launch_bounds__(512) void k_aggregate(
    const __half* __restrict__ y, const int* __restrict__ offs,
    const int* __restrict__ csr_src, const float* __restrict__ rs_in,
    const float* __restrict__ bvec, float* __restrict__ out, int N) {
  __shared__ float agg[16 * 513];
  int tid = threadIdx.x;
  int lane = tid & 63, wave = tid >> 6;   // 8 waves
  int n0 = blockIdx.x * 16;

#define ACC_EDGE(s)                                                          \
  {                                                                          \
    const uint2* rp = (const uint2*)(y + (size_t)(s) * 512);                 \
    uint2 ua = rp[lane];                                                     \
    uint2 ub = rp[64 + lane];                                                \
    float2 f;                                                                \
    f = __half22float2(*(const __half2*)&ua.x); accA.x += f.x; accA.y += f.y;\
    f = __half22float2(*(const __half2*)&ua.y); accA.z += f.x; accA.w += f.y;\
    f = __half22float2(*(const __half2*)&ub.x); accB.x += f.x; accB.y += f.y;\
    f = __half22float2(*(const __half2*)&ub.y); accB.z += f.x; accB.w += f.y;\
  }

  #pragma unroll
  for (int k = 0; k < 2; ++k) {
    int nl = k * 8 + wave;
    int n = n0 + nl;
    float4 accA = {0.f, 0.f, 0.f, 0.f};
    float4 accB = {0.f, 0.f, 0.f, 0.f};
    if (n < N) {
      int j0 = offs[n], j1 = offs[n + 1];
      for (int base = j0; base < j1; base += 64) {
        int idxv = csr_src[base + lane];  // coalesced block of up to 64 indices
        int m = j1 - base; if (m > 64) m = 64;
        int e = 0;
        for (; e + 3 < m; e += 4) {
          int s0 = __builtin_amdgcn_readlane(idxv, e);
          int s1 = __builtin_amdgcn_readlane(idxv, e + 1);
          int s2 = __builtin_amdgcn_readlane(idxv, e + 2);
          int s3 = __builtin_amdgcn_readlane(idxv, e + 3);
          ACC_EDGE(s0); ACC_EDGE(s1); ACC_EDGE(s2); ACC_EDGE(s3);
        }
        for (; e < m; ++e) {
          int s0 = __builtin_amdgcn_readlane(idxv, e);
          ACC_EDGE(s0);
        }
      }
    }
    *(float4*)&agg[nl * 513 + lane * 4] = accA;
    *(float4*)&agg[nl * 513 + 256 + lane * 4] = accB;
  }
#undef ACC_EDGE
  __syncthreads();

  // epilogue: scale, bias, relu, transpose-back; NONTEMPORAL stores so the
  // 100MB out stream doesn't evict y (51MB) from L2/L3.
  int nl = tid & 15;
  int r0 = tid >> 4;  // 0..31
  int n = n0 + nl;
  float rs = (n < N) ? rs_in[n] : 0.0f;
  #pragma unroll 4
  for (int it = 0; it < 16; ++it) {
    int c = it * 32 + r0;          // c = (b*4+t)*64 + f
    float v = agg[nl * 513 + c];
    int f = c & 63, bt = c >> 6;
    int b = bt >> 2, t = bt & 3;
    v = v * rs + bvec[f];
    v = fmaxf(v, 0.0f);
    if (n < N)
      __builtin_nontemporal_store(v, &out[(size_t)((b * 64 + f) * 4 + t) * (size_t)N + n]);
  }
}

extern "C" void kernel_launch(void* const* d_in, const int* in_sizes, int n_in,
                              void* d_out, int out_size, void* d_ws, size_t ws_size,
                              hipStream_t stream) {
  const float* in_feat = (const float*)d_in[0];
  const int*   src     = (const int*)d_in[1];
  const int*   dst     = (const int*)d_in[2];
  const float* W       = (const float*)d_in[3];
  const float* bvec    = (const float*)d_in[4];
  float* out = (float*)d_out;

  int N = in_sizes[0] / 512;   // B*H*T = 2*64*4 = 512
  int E = in_sizes[1];

  int A  = (N + 64) & ~63;     // room for N+1 offsets, 64-aligned
  int EA = (E + 63) & ~63;
  int M  = (N + 255) / 256;    // scan blocks (<= 256 for N <= 65536)

  // layout: the three arrays needing zero-init come first (one memset)
  int*   deg_out_i = (int*)d_ws;        // [A]  zeroed
  int*   deg_in_i  = deg_out_i + A;     // [A]  zeroed
  int*   cursor    = deg_in_i + A;      // [A]  zeroed
  int*   offs      = cursor + A;        // [A] (N+1 used, fully written by scans)
  int*   bsum      = offs + A;          // [256]
  int*   boffs     = bsum + 256;        // [256]
  float* rs_out    = (float*)(boffs + 256);
  float* rs_in     = rs_out + A;
  int*   csr_src   = (int*)(rs_in + A); // [EA] (+slack: y follows, overreads safe)
  __half* y        = (__half*)(csr_src + EA); // [N*512] fp16, plain layout

  hipMemsetAsync(deg_out_i, 0, (size_t)(3 * A) * sizeof(int), stream);
  hipLaunchKernelGGL(k_deg, dim3((E + 255) / 256), dim3(256), 0, stream,
                     src, dst, deg_out_i, deg_in_i, E);
  hipLaunchKernelGGL(k_scan1, dim3(M), dim3(256), 0, stream,
                     deg_in_i, deg_out_i, bsum, rs_out, rs_in, N);
  hipLaunchKernelGGL(k_scan2, dim3(1), dim3(256), 0, stream, bsum, boffs, offs, M, N);
  hipLaunchKernelGGL(k_scan3, dim3(M), dim3(256), 0, stream, deg_in_i, boffs, offs, N);
  hipLaunchKernelGGL(k_scatter, dim3((E + 255) / 256), dim3(256), 0, stream,
                     src, dst, offs, cursor, csr_src, E);
  hipLaunchKernelGGL(k_transform, dim3((N + 15) / 16, 2), dim3(128), 0, stream,
                     in_feat, W, rs_out, y, N);
  hipLaunchKernelGGL(k_aggregate, dim3((N + 15) / 16), dim3(512), 0, stream,
                     y, offs, csr_src, rs_in, bvec, out, N);
}

// Round 18
// 181.490 us; speedup vs baseline: 1.0131x; 1.0131x over previous
//
#include <hip/hip_runtime.h>
#include <hip/hip_fp16.h>

// ---------------------------------------------------------------------------
// GCN layer: out[b][f][t][n] = relu( rsqrt(deg_in[n]) *
//     sum_{e: dst[e]=n} ( rsqrt(deg_out[src[e]]) * x[src[e]] @ W )[b][t][f] + bias[f] )
// Strategy: (1) degrees+CSR, (2) MFMA transform -> y[n][512] fp16 plain
//           node-major, (3) CSR gather-sum + epilogue + transpose-back.
// R18: transform was STORE-ISSUE bound: 32x 2B scalar y-stores/thread =
//      25.6M store instrs ~= 42us of issue. Now: MFMA results staged in an
//      8KB LDS tile (16 nodes x 256 ch), then written as 4x uint4/thread
//      (3.2M instrs). R17's NT-store aggregate kept (72.3us best).
// ---------------------------------------------------------------------------

typedef _Float16 half8 __attribute__((ext_vector_type(8)));
typedef float f32x4 __attribute__((ext_vector_type(4)));

extern "C" __global__ void k_deg(const int* __restrict__ src, const int* __restrict__ dst,
                                 int* __restrict__ deg_out, int* __restrict__ deg_in, int E) {
  int e = blockIdx.x * blockDim.x + threadIdx.x;
  if (e < E) {
    atomicAdd(&deg_out[src[e]], 1);
    atomicAdd(&deg_in[dst[e]], 1);
  }
}

// scan1 + rsqrt fused: block sums of deg_in, plus rs arrays.
extern "C" __global__ __launch_bounds__(256) void k_scan1(const int* __restrict__ deg_in,
                                                          const int* __restrict__ deg_out,
                                                          int* __restrict__ bsum,
                                                          float* __restrict__ rs_out,
                                                          float* __restrict__ rs_in, int N) {
  __shared__ int red[256];
  int tid = threadIdx.x;
  int i = blockIdx.x * 256 + tid;
  int di = (i < N) ? deg_in[i] : 0;
  red[tid] = di;
  if (i < N) {
    int a = deg_out[i] > 1 ? deg_out[i] : 1;
    int b = di > 1 ? di : 1;
    rs_out[i] = rsqrtf((float)a);
    rs_in[i]  = rsqrtf((float)b);
  }
  __syncthreads();
  #pragma unroll
  for (int off = 128; off > 0; off >>= 1) {
    if (tid < off) red[tid] += red[tid + off];
    __syncthreads();
  }
  if (tid == 0) bsum[blockIdx.x] = red[0];
}

extern "C" __global__ __launch_bounds__(256) void k_scan2(const int* __restrict__ bsum,
                                                          int* __restrict__ boffs,
                                                          int* __restrict__ offs, int M, int N) {
  __shared__ int sc[256];
  int tid = threadIdx.x;
  int v = (tid < M) ? bsum[tid] : 0;
  sc[tid] = v;
  __syncthreads();
  #pragma unroll
  for (int off = 1; off < 256; off <<= 1) {
    int t = sc[tid];
    if (tid >= off) t += sc[tid - off];
    __syncthreads();
    sc[tid] = t;
    __syncthreads();
  }
  boffs[tid] = sc[tid] - v;           // exclusive block offset
  if (tid == 255) offs[N] = sc[255];  // total edge count
}

extern "C" __global__ __launch_bounds__(256) void k_scan3(const int* __restrict__ deg,
                                                          const int* __restrict__ boffs,
                                                          int* __restrict__ offs, int N) {
  __shared__ int sc[256];
  int tid = threadIdx.x;
  int i = blockIdx.x * 256 + tid;
  int v = (i < N) ? deg[i] : 0;
  sc[tid] = v;
  __syncthreads();
  #pragma unroll
  for (int off = 1; off < 256; off <<= 1) {
    int t = sc[tid];
    if (tid >= off) t += sc[tid - off];
    __syncthreads();
    sc[tid] = t;
    __syncthreads();
  }
  if (i < N) offs[i] = boffs[blockIdx.x] + sc[tid] - v;
}

extern "C" __global__ void k_scatter(const int* __restrict__ src, const int* __restrict__ dst,
                                     const int* __restrict__ offs, int* __restrict__ cursor,
                                     int* __restrict__ csr_src, int E) {
  int e = blockIdx.x * blockDim.x + threadIdx.x;
  if (e < E) {
    int d = dst[e];
    int pos = offs[d] + atomicAdd(&cursor[d], 1);
    csr_src[pos] = src[e];
  }
}

// MFMA transform (R18). Block = 128 thr = 2 waves; grid (N/16, 2). Block
// covers 16 nodes x bt quad blockIdx.y*4..+3 (wave w -> bt w*2+{0,1}).
// W frags in VGPRs, cross-bt A prefetch (R16). Results staged in LDS
// (16 nodes x 256 ch fp16, row pad 8 halfs for uint4-aligned rows), then
// stored to y as 4x uint4 per thread (fully coalesced).
extern "C" __global__ __launch_bounds__(128) void k_transform(
    const float* __restrict__ in_feat, const float* __restrict__ W,
    const float* __restrict__ rs_out, __half* __restrict__ y, int N) {
  __shared__ __half ytile[16][264];   // 256 ch + 8 pad (row stride 528B, 16B-aligned)
  int tid = threadIdx.x;
  int wave = tid >> 6, l = tid & 63;
  int col = l & 15;      // A row (node) on load side; D col (f) on store side
  int kg  = l >> 4;      // k-group 0..3
  int n0 = blockIdx.x * 16;
  int btbase = blockIdx.y * 4 + wave * 2;   // bt = btbase, btbase+1

  half8 wf[4][2];
  #pragma unroll
  for (int ft = 0; ft < 4; ++ft)
    #pragma unroll
    for (int ks = 0; ks < 2; ++ks)
      #pragma unroll
      for (int j = 0; j < 8; ++j)
        wf[ft][ks][j] = (_Float16)W[(ks * 32 + kg * 8 + j) * 64 + ft * 16 + col];

  int nA = n0 + col;
  bool okA = (nA < N);
  float rs = okA ? rs_out[nA] : 0.0f;
  size_t hs = (size_t)4 * (size_t)N;

  float c0[8], c1[8], nx0[8], nx1[8];
  {
    int bt = btbase, b = bt >> 2, t = bt & 3;
    const float* xp = in_feat + (size_t)(b * 256 + t) * (size_t)N + nA;
    #pragma unroll
    for (int j = 0; j < 8; ++j) c0[j] = okA ? xp[(size_t)(kg * 8 + j) * hs] : 0.0f;
    #pragma unroll
    for (int j = 0; j < 8; ++j) c1[j] = okA ? xp[(size_t)(32 + kg * 8 + j) * hs] : 0.0f;
  }

  #pragma unroll
  for (int p = 0; p < 2; ++p) {
    if (p == 0) {  // prefetch bt+1's A-fragments before consuming bt's
      int bt = btbase + 1, b = bt >> 2, t = bt & 3;
      const float* xp = in_feat + (size_t)(b * 256 + t) * (size_t)N + nA;
      #pragma unroll
      for (int j = 0; j < 8; ++j) nx0[j] = okA ? xp[(size_t)(kg * 8 + j) * hs] : 0.0f;
      #pragma unroll
      for (int j = 0; j < 8; ++j) nx1[j] = okA ? xp[(size_t)(32 + kg * 8 + j) * hs] : 0.0f;
    }
    int btloc = wave * 2 + p;   // 0..3 within the block's bt quad

    half8 a0, a1;
    #pragma unroll
    for (int j = 0; j < 8; ++j) {
      a0[j] = (_Float16)(c0[j] * rs);
      a1[j] = (_Float16)(c1[j] * rs);
    }

    #pragma unroll
    for (int ft = 0; ft < 4; ++ft) {
      f32x4 acc = {0.f, 0.f, 0.f, 0.f};
      acc = __builtin_amdgcn_mfma_f32_16x16x32_f16(a0, wf[ft][0], acc, 0, 0, 0);
      acc = __builtin_amdgcn_mfma_f32_16x16x32_f16(a1, wf[ft][1], acc, 0, 0, 0);
      #pragma unroll
      for (int r = 0; r < 4; ++r)
        ytile[kg * 4 + r][btloc * 64 + ft * 16 + col] = __float2half(acc[r]);
    }

    if (p == 0) {
      #pragma unroll
      for (int j = 0; j < 8; ++j) { c0[j] = nx0[j]; c1[j] = nx1[j]; }
    }
  }
  __syncthreads();

  // vectorized y store: row = tid>>3 (16 rows), seg = tid&7; 4x uint4/thread
  int row = tid >> 3, seg = tid & 7;
  int nr = n0 + row;
  if (nr < N) {
    const uint4* lp = (const uint4*)&ytile[row][0];   // 32 uint4 per row
    uint4* gp = (uint4*)(y + (size_t)nr * 512 + blockIdx.y * 256);
    #pragma unroll
    for (int q = 0; q < 4; ++q) gp[seg + q * 8] = lp[seg + q * 8];
  }
}

// Aggregate (R9 body + R17 NT out stores — 72.3us best). 512 threads = 8
// waves; wave handles 2 nodes (16-node tile, 33KB LDS -> 4 blocks/CU).
// Per edge: 2x8B loads (channels 4l..4l+3 and 256+4l..+3), unroll 4.
extern "C" __global__ __launch_bounds__(512) void k_aggregate(
    const __half* __restrict__ y, const int* __restrict__ offs,
    const int* __restrict__ csr_src, const float* __restrict__ rs_in,
    const float* __restrict__ bvec, float* __restrict__ out, int N) {
  __shared__ float agg[16 * 513];
  int tid = threadIdx.x;
  int lane = tid & 63, wave = tid >> 6;   // 8 waves
  int n0 = blockIdx.x * 16;

#define ACC_EDGE(s)                                                          \
  {                                                                          \
    const uint2* rp = (const uint2*)(y + (size_t)(s) * 512);                 \
    uint2 ua = rp[lane];                                                     \
    uint2 ub = rp[64 + lane];                                                \
    float2 f;                                                                \
    f = __half22float2(*(const __half2*)&ua.x); accA.x += f.x; accA.y += f.y;\
    f = __half22float2(*(const __half2*)&ua.y); accA.z += f.x; accA.w += f.y;\
    f = __half22float2(*(const __half2*)&ub.x); accB.x += f.x; accB.y += f.y;\
    f = __half22float2(*(const __half2*)&ub.y); accB.z += f.x; accB.w += f.y;\
  }

  #pragma unroll
  for (int k = 0; k < 2; ++k) {
    int nl = k * 8 + wave;
    int n = n0 + nl;
    float4 accA = {0.f, 0.f, 0.f, 0.f};
    float4 accB = {0.f, 0.f, 0.f, 0.f};
    if (n < N) {
      int j0 = offs[n], j1 = offs[n + 1];
      for (int base = j0; base < j1; base += 64) {
        int idxv = csr_src[base + lane];  // coalesced block of up to 64 indices
        int m = j1 - base; if (m > 64) m = 64;
        int e = 0;
        for (; e + 3 < m; e += 4) {
          int s0 = __builtin_amdgcn_readlane(idxv, e);
          int s1 = __builtin_amdgcn_readlane(idxv, e + 1);
          int s2 = __builtin_amdgcn_readlane(idxv, e + 2);
          int s3 = __builtin_amdgcn_readlane(idxv, e + 3);
          ACC_EDGE(s0); ACC_EDGE(s1); ACC_EDGE(s2); ACC_EDGE(s3);
        }
        for (; e < m; ++e) {
          int s0 = __builtin_amdgcn_readlane(idxv, e);
          ACC_EDGE(s0);
        }
      }
    }
    *(float4*)&agg[nl * 513 + lane * 4] = accA;
    *(float4*)&agg[nl * 513 + 256 + lane * 4] = accB;
  }
#undef ACC_EDGE
  __syncthreads();

  // epilogue: scale, bias, relu, transpose-back; NT stores (R17).
  int nl = tid & 15;
  int r0 = tid >> 4;  // 0..31
  int n = n0 + nl;
  float rs = (n < N) ? rs_in[n] : 0.0f;
  #pragma unroll 4
  for (int it = 0; it < 16; ++it) {
    int c = it * 32 + r0;          // c = (b*4+t)*64 + f
    float v = agg[nl * 513 + c];
    int f = c & 63, bt = c >> 6;
    int b = bt >> 2, t = bt & 3;
    v = v * rs + bvec[f];
    v = fmaxf(v, 0.0f);
    if (n < N)
      __builtin_nontemporal_store(v, &out[(size_t)((b * 64 + f) * 4 + t) * (size_t)N + n]);
  }
}

extern "C" void kernel_launch(void* const* d_in, const int* in_sizes, int n_in,
                              void* d_out, int out_size, void* d_ws, size_t ws_size,
                              hipStream_t stream) {
  const float* in_feat = (const float*)d_in[0];
  const int*   src     = (const int*)d_in[1];
  const int*   dst     = (const int*)d_in[2];
  const float* W       = (const float*)d_in[3];
  const float* bvec    = (const float*)d_in[4];
  float* out = (float*)d_out;

  int N = in_sizes[0] / 512;   // B*H*T = 2*64*4 = 512
  int E = in_sizes[1];

  int A  = (N + 64) & ~63;     // room for N+1 offsets, 64-aligned
  int EA = (E + 63) & ~63;
  int M  = (N + 255) / 256;    // scan blocks (<= 256 for N <= 65536)

  // layout: the three arrays needing zero-init come first (one memset)
  int*   deg_out_i = (int*)d_ws;        // [A]  zeroed
  int*   deg_in_i  = deg_out_i + A;     // [A]  zeroed
  int*   cursor    = deg_in_i + A;      // [A]  zeroed
  int*   offs      = cursor + A;        // [A] (N+1 used, fully written by scans)
  int*   bsum      = offs + A;          // [256]
  int*   boffs     = bsum + 256;        // [256]
  float* rs_out    = (float*)(boffs + 256);
  float* rs_in     = rs_out + A;
  int*   csr_src   = (int*)(rs_in + A); // [EA] (+slack: y follows, overreads safe)
  __half* y        = (__half*)(csr_src + EA); // [N*512] fp16, plain layout

  hipMemsetAsync(deg_out_i, 0, (size_t)(3 * A) * sizeof(int), stream);
  hipLaunchKernelGGL(k_deg, dim3((E + 255) / 256), dim3(256), 0, stream,
                     src, dst, deg_out_i, deg_in_i, E);
  hipLaunchKernelGGL(k_scan1, dim3(M), dim3(256), 0, stream,
                     deg_in_i, deg_out_i, bsum, rs_out, rs_in, N);
  hipLaunchKernelGGL(k_scan2, dim3(1), dim3(256), 0, stream, bsum, boffs, offs, M, N);
  hipLaunchKernelGGL(k_scan3, dim3(M), dim3(256), 0, stream, deg_in_i, boffs, offs, N);
  hipLaunchKernelGGL(k_scatter, dim3((E + 255) / 256), dim3(256), 0, stream,
                     src, dst, offs, cursor, csr_src, E);
  hipLaunchKernelGGL(k_transform, dim3((N + 15) / 16, 2), dim3(128), 0, stream,
                     in_feat, W, rs_out, y, N);
  hipLaunchKernelGGL(k_aggregate, dim3((N + 15) / 16), dim3(512), 0, stream,
                     y, offs, csr_src, rs_in, bvec, out, N);
}

// Round 19
// 179.966 us; speedup vs baseline: 1.0216x; 1.0085x over previous
//
#include <hip/hip_runtime.h>
#include <hip/hip_fp16.h>

// ---------------------------------------------------------------------------
// GCN layer: out[b][f][t][n] = relu( rsqrt(deg_in[n]) *
//     sum_{e: dst[e]=n} ( rsqrt(deg_out[src[e]]) * x[src[e]] @ W )[b][t][f] + bias[f] )
// Strategy: (1) degrees+CSR, (2) MFMA transform -> y[n][512] fp16 plain
//           node-major, (3) CSR gather-sum + epilogue + transpose-back.
// R19: setup-only round. scan2 launch eliminated (scan3 scans the 196-entry
//      bsum locally per block); scan3 preloads cursor[i]=offs[i] so scatter
//      is a single atomicAdd (no offs-read stream); memset 3A->2A.
//      Transform = R18 (MFMA + LDS-staged y store). Aggregate = R17
//      (R9 body + NT out stores, 72.3us — L2-miss-fabric pinned, frozen).
// ---------------------------------------------------------------------------

typedef _Float16 half8 __attribute__((ext_vector_type(8)));
typedef float f32x4 __attribute__((ext_vector_type(4)));

extern "C" __global__ void k_deg(const int* __restrict__ src, const int* __restrict__ dst,
                                 int* __restrict__ deg_out, int* __restrict__ deg_in, int E) {
  int e = blockIdx.x * blockDim.x + threadIdx.x;
  if (e < E) {
    atomicAdd(&deg_out[src[e]], 1);
    atomicAdd(&deg_in[dst[e]], 1);
  }
}

// scan1 + rsqrt fused: block sums of deg_in, plus rs arrays.
extern "C" __global__ __launch_bounds__(256) void k_scan1(const int* __restrict__ deg_in,
                                                          const int* __restrict__ deg_out,
                                                          int* __restrict__ bsum,
                                                          float* __restrict__ rs_out,
                                                          float* __restrict__ rs_in, int N) {
  __shared__ int red[256];
  int tid = threadIdx.x;
  int i = blockIdx.x * 256 + tid;
  int di = (i < N) ? deg_in[i] : 0;
  red[tid] = di;
  if (i < N) {
    int a = deg_out[i] > 1 ? deg_out[i] : 1;
    int b = di > 1 ? di : 1;
    rs_out[i] = rsqrtf((float)a);
    rs_in[i]  = rsqrtf((float)b);
  }
  __syncthreads();
  #pragma unroll
  for (int off = 128; off > 0; off >>= 1) {
    if (tid < off) red[tid] += red[tid + off];
    __syncthreads();
  }
  if (tid == 0) bsum[blockIdx.x] = red[0];
}

// scan3 (scan2 folded in): per-node exclusive scan within block + local scan
// of bsum for the block offset. Writes offs[i] AND cursor[i]=offs[i].
// Block 0 thread 0 writes offs[N] = total.
extern "C" __global__ __launch_bounds__(256) void k_scan3(const int* __restrict__ deg,
                                                          const int* __restrict__ bsum,
                                                          int* __restrict__ offs,
                                                          int* __restrict__ cursor,
                                                          int M, int N) {
  __shared__ int sc[256];
  __shared__ int bs[256];
  int tid = threadIdx.x;

  // local exclusive-scan of bsum (tiny: M <= 256)
  int bv = (tid < M) ? bsum[tid] : 0;
  bs[tid] = bv;
  __syncthreads();
  #pragma unroll
  for (int off = 1; off < 256; off <<= 1) {
    int t = bs[tid];
    if (tid >= off) t += bs[tid - off];
    __syncthreads();
    bs[tid] = t;
    __syncthreads();
  }
  int boff = (blockIdx.x > 0) ? bs[blockIdx.x - 1] : 0;
  if (blockIdx.x == 0 && tid == 0) offs[N] = bs[255];  // total edges

  int i = blockIdx.x * 256 + tid;
  int v = (i < N) ? deg[i] : 0;
  sc[tid] = v;
  __syncthreads();
  #pragma unroll
  for (int off = 1; off < 256; off <<= 1) {
    int t = sc[tid];
    if (tid >= off) t += sc[tid - off];
    __syncthreads();
    sc[tid] = t;
    __syncthreads();
  }
  if (i < N) {
    int o = boff + sc[tid] - v;
    offs[i] = o;
    cursor[i] = o;   // preload for scatter's single-atomic path
  }
}

extern "C" __global__ void k_scatter(const int* __restrict__ src, const int* __restrict__ dst,
                                     int* __restrict__ cursor,
                                     int* __restrict__ csr_src, int E) {
  int e = blockIdx.x * blockDim.x + threadIdx.x;
  if (e < E) {
    int pos = atomicAdd(&cursor[dst[e]], 1);
    csr_src[pos] = src[e];
  }
}

// MFMA transform (R18). Block = 128 thr = 2 waves; grid (N/16, 2). Block
// covers 16 nodes x bt quad blockIdx.y*4..+3 (wave w -> bt w*2+{0,1}).
// W frags in VGPRs, cross-bt A prefetch (R16). Results staged in LDS
// (16 nodes x 256 ch fp16, row pad 8), then 4x uint4 stores per thread.
extern "C" __global__ __launch_bounds__(128) void k_transform(
    const float* __restrict__ in_feat, const float* __restrict__ W,
    const float* __restrict__ rs_out, __half* __restrict__ y, int N) {
  __shared__ __half ytile[16][264];   // 256 ch + 8 pad (row stride 528B, 16B-aligned)
  int tid = threadIdx.x;
  int wave = tid >> 6, l = tid & 63;
  int col = l & 15;      // A row (node) on load side; D col (f) on store side
  int kg  = l >> 4;      // k-group 0..3
  int n0 = blockIdx.x * 16;
  int btbase = blockIdx.y * 4 + wave * 2;   // bt = btbase, btbase+1

  half8 wf[4][2];
  #pragma unroll
  for (int ft = 0; ft < 4; ++ft)
    #pragma unroll
    for (int ks = 0; ks < 2; ++ks)
      #pragma unroll
      for (int j = 0; j < 8; ++j)
        wf[ft][ks][j] = (_Float16)W[(ks * 32 + kg * 8 + j) * 64 + ft * 16 + col];

  int nA = n0 + col;
  bool okA = (nA < N);
  float rs = okA ? rs_out[nA] : 0.0f;
  size_t hs = (size_t)4 * (size_t)N;

  float c0[8], c1[8], nx0[8], nx1[8];
  {
    int bt = btbase, b = bt >> 2, t = bt & 3;
    const float* xp = in_feat + (size_t)(b * 256 + t) * (size_t)N + nA;
    #pragma unroll
    for (int j = 0; j < 8; ++j) c0[j] = okA ? xp[(size_t)(kg * 8 + j) * hs] : 0.0f;
    #pragma unroll
    for (int j = 0; j < 8; ++j) c1[j] = okA ? xp[(size_t)(32 + kg * 8 + j) * hs] : 0.0f;
  }

  #pragma unroll
  for (int p = 0; p < 2; ++p) {
    if (p == 0) {  // prefetch bt+1's A-fragments before consuming bt's
      int bt = btbase + 1, b = bt >> 2, t = bt & 3;
      const float* xp = in_feat + (size_t)(b * 256 + t) * (size_t)N + nA;
      #pragma unroll
      for (int j = 0; j < 8; ++j) nx0[j] = okA ? xp[(size_t)(kg * 8 + j) * hs] : 0.0f;
      #pragma unroll
      for (int j = 0; j < 8; ++j) nx1[j] = okA ? xp[(size_t)(32 + kg * 8 + j) * hs] : 0.0f;
    }
    int btloc = wave * 2 + p;   // 0..3 within the block's bt quad

    half8 a0, a1;
    #pragma unroll
    for (int j = 0; j < 8; ++j) {
      a0[j] = (_Float16)(c0[j] * rs);
      a1[j] = (_Float16)(c1[j] * rs);
    }

    #pragma unroll
    for (int ft = 0; ft < 4; ++ft) {
      f32x4 acc = {0.f, 0.f, 0.f, 0.f};
      acc = __builtin_amdgcn_mfma_f32_16x16x32_f16(a0, wf[ft][0], acc, 0, 0, 0);
      acc = __builtin_amdgcn_mfma_f32_16x16x32_f16(a1, wf[ft][1], acc, 0, 0, 0);
      #pragma unroll
      for (int r = 0; r < 4; ++r)
        ytile[kg * 4 + r][btloc * 64 + ft * 16 + col] = __float2half(acc[r]);
    }

    if (p == 0) {
      #pragma unroll
      for (int j = 0; j < 8; ++j) { c0[j] = nx0[j]; c1[j] = nx1[j]; }
    }
  }
  __syncthreads();

  // vectorized y store: row = tid>>3 (16 rows), seg = tid&7; 4x uint4/thread
  int row = tid >> 3, seg = tid & 7;
  int nr = n0 + row;
  if (nr < N) {
    const uint4* lp = (const uint4*)&ytile[row][0];   // 32 uint4 per row
    uint4* gp = (uint4*)(y + (size_t)nr * 512 + blockIdx.y * 256);
    #pragma unroll
    for (int q = 0; q < 4; ++q) gp[seg + q * 8] = lp[seg + q * 8];
  }
}

// Aggregate (R9 body + R17 NT out stores — 72.3us, fabric-pinned, frozen).
extern "C" __global__ __launch_bounds__(512) void k_aggregate(
    const __half* __restrict__ y, const int* __restrict__ offs,
    const int* __restrict__ csr_src, const float* __restrict__ rs_in,
    const float* __restrict__ bvec, float* __restrict__ out, int N) {
  __shared__ float agg[16 * 513];
  int tid = threadIdx.x;
  int lane = tid & 63, wave = tid >> 6;   // 8 waves
  int n0 = blockIdx.x * 16;

#define ACC_EDGE(s)                                                          \
  {                                                                          \
    const uint2* rp = (const uint2*)(y + (size_t)(s) * 512);                 \
    uint2 ua = rp[lane];                                                     \
    uint2 ub = rp[64 + lane];                                                \
    float2 f;                                                                \
    f = __half22float2(*(const __half2*)&ua.x); accA.x += f.x; accA.y += f.y;\
    f = __half22float2(*(const __half2*)&ua.y); accA.z += f.x; accA.w += f.y;\
    f = __half22float2(*(const __half2*)&ub.x); accB.x += f.x; accB.y += f.y;\
    f = __half22float2(*(const __half2*)&ub.y); accB.z += f.x; accB.w += f.y;\
  }

  #pragma unroll
  for (int k = 0; k < 2; ++k) {
    int nl = k * 8 + wave;
    int n = n0 + nl;
    float4 accA = {0.f, 0.f, 0.f, 0.f};
    float4 accB = {0.f, 0.f, 0.f, 0.f};
    if (n < N) {
      int j0 = offs[n], j1 = offs[n + 1];
      for (int base = j0; base < j1; base += 64) {
        int idxv = csr_src[base + lane];  // coalesced block of up to 64 indices
        int m = j1 - base; if (m > 64) m = 64;
        int e = 0;
        for (; e + 3 < m; e += 4) {
          int s0 = __builtin_amdgcn_readlane(idxv, e);
          int s1 = __builtin_amdgcn_readlane(idxv, e + 1);
          int s2 = __builtin_amdgcn_readlane(idxv, e + 2);
          int s3 = __builtin_amdgcn_readlane(idxv, e + 3);
          ACC_EDGE(s0); ACC_EDGE(s1); ACC_EDGE(s2); ACC_EDGE(s3);
        }
        for (; e < m; ++e) {
          int s0 = __builtin_amdgcn_readlane(idxv, e);
          ACC_EDGE(s0);
        }
      }
    }
    *(float4*)&agg[nl * 513 + lane * 4] = accA;
    *(float4*)&agg[nl * 513 + 256 + lane * 4] = accB;
  }
#undef ACC_EDGE
  __syncthreads();

  // epilogue: scale, bias, relu, transpose-back; NT stores (R17).
  int nl = tid & 15;
  int r0 = tid >> 4;  // 0..31
  int n = n0 + nl;
  float rs = (n < N) ? rs_in[n] : 0.0f;
  #pragma unroll 4
  for (int it = 0; it < 16; ++it) {
    int c = it * 32 + r0;          // c = (b*4+t)*64 + f
    float v = agg[nl * 513 + c];
    int f = c & 63, bt = c >> 6;
    int b = bt >> 2, t = bt & 3;
    v = v * rs + bvec[f];
    v = fmaxf(v, 0.0f);
    if (n < N)
      __builtin_nontemporal_store(v, &out[(size_t)((b * 64 + f) * 4 + t) * (size_t)N + n]);
  }
}

extern "C" void kernel_launch(void* const* d_in, const int* in_sizes, int n_in,
                              void* d_out, int out_size, void* d_ws, size_t ws_size,
                              hipStream_t stream) {
  const float* in_feat = (const float*)d_in[0];
  const int*   src     = (const int*)d_in[1];
  const int*   dst     = (const int*)d_in[2];
  const float* W       = (const float*)d_in[3];
  const float* bvec    = (const float*)d_in[4];
  float* out = (float*)d_out;

  int N = in_sizes[0] / 512;   // B*H*T = 2*64*4 = 512
  int E = in_sizes[1];

  int A  = (N + 64) & ~63;     // room for N+1 offsets, 64-aligned
  int EA = (E + 63) & ~63;
  int M  = (N + 255) / 256;    // scan blocks (<= 256 for N <= 65536)

  // layout: the two arrays needing zero-init come first (one memset)
  int*   deg_out_i = (int*)d_ws;        // [A]  zeroed
  int*   deg_in_i  = deg_out_i + A;     // [A]  zeroed
  int*   cursor    = deg_in_i + A;      // [A]  written by scan3
  int*   offs      = cursor + A;        // [A]  (N+1 used, written by scan3)
  int*   bsum      = offs + A;          // [256]
  float* rs_out    = (float*)(bsum + 256);
  float* rs_in     = rs_out + A;
  int*   csr_src   = (int*)(rs_in + A); // [EA] (+slack: y follows, overreads safe)
  __half* y        = (__half*)(csr_src + EA); // [N*512] fp16, plain layout

  hipMemsetAsync(deg_out_i, 0, (size_t)(2 * A) * sizeof(int), stream);
  hipLaunchKernelGGL(k_deg, dim3((E + 255) / 256), dim3(256), 0, stream,
                     src, dst, deg_out_i, deg_in_i, E);
  hipLaunchKernelGGL(k_scan1, dim3(M), dim3(256), 0, stream,
                     deg_in_i, deg_out_i, bsum, rs_out, rs_in, N);
  hipLaunchKernelGGL(k_scan3, dim3(M), dim3(256), 0, stream,
                     deg_in_i, bsum, offs, cursor, M, N);
  hipLaunchKernelGGL(k_scatter, dim3((E + 255) / 256), dim3(256), 0, stream,
                     src, dst, cursor, csr_src, E);
  hipLaunchKernelGGL(k_transform, dim3((N + 15) / 16, 2), dim3(128), 0, stream,
                     in_feat, W, rs_out, y, N);
  hipLaunchKernelGGL(k_aggregate, dim3((N + 15) / 16), dim3(512), 0, stream,
                     y, offs, csr_src, rs_in, bvec, out, N);
}